// Round 10
// baseline (4693.009 us; speedup 1.0000x reference)
//
#include <hip/hip_runtime.h>
#include <math.h>

#define LL 256
#define BB 256
#define HH 256
#define CC 16
#define YY 32
#define HC (HH*CC)     // 4096
#define NSTEP (LL-1)   // 255
#define NBG 32         // batch groups
#define BGB 8          // batches per group
#define HCH 32         // h per chunk (=> 512 W2 cols per block)
#define TPB 1024
#define NJS 8          // phase-B j-split slices

typedef __attribute__((ext_vector_type(4))) float f32x4;

// fast tanh — IDENTICAL to the passing baseline (bit-exact frozen).
__device__ __forceinline__ float fast_tanh(float x) {
    float e = __expf(2.0f * x);
    return 1.0f - 2.0f / (e + 1.0f);
}

// coherence-point (device-coherent) access: bypasses the non-coherent
// per-XCD L2s. Used ONLY for the small cross-block z / hid exchange.
__device__ __forceinline__ float2 ld_coh2(const float* p) {
    union { unsigned long long u; float2 f; } cv;
    cv.u = __hip_atomic_load((const unsigned long long*)p,
                             __ATOMIC_RELAXED, __HIP_MEMORY_SCOPE_AGENT);
    return cv.f;
}
__device__ __forceinline__ void st_coh(float* p, float v) {
    __hip_atomic_store(p, v, __ATOMIC_RELAXED, __HIP_MEMORY_SCOPE_AGENT);
}

// 8-way sibling barrier, monotonic per-group counter (no reset).
// __syncthreads() drains vmem (vmcnt(0) before s_barrier) so all coherent
// stores are visible before the arrival add. 32 groups on 32 distinct lines.
__device__ __forceinline__ void bg_barrier(unsigned* cnt, unsigned target) {
    __syncthreads();
    if (threadIdx.x == 0) {
        __hip_atomic_fetch_add(cnt, 1u, __ATOMIC_RELAXED, __HIP_MEMORY_SCOPE_AGENT);
        while (__hip_atomic_load(cnt, __ATOMIC_RELAXED, __HIP_MEMORY_SCOPE_AGENT) < target)
            __builtin_amdgcn_s_sleep(1);
    }
    __syncthreads();
}

// ---------------------------------------------------------------------------
// persistent scan: 256 blocks = 32 bg x 8 hc, 1024 threads, 1 block/CU
// (LDS 147 KB). __launch_bounds__(TPB,4): 128-VGPR cap, no spill (r6-proven).
// r6 STRUCTURE FROZEN (passing, absmax 0.03417969). Single delta this round:
// during the hid-barrier wait, each wave prefetches its W2 slice's first 8
// j-rows into the (momentarily dead) psum LDS region; phase B reads jq 0..7
// from LDS and jq 8..31 from global. W2 is constant -> identical f32 values
// feed the identical accumulation chains. Zero arithmetic change.
// ---------------------------------------------------------------------------
__global__ void __launch_bounds__(TPB, 4)
k_scan(const float* __restrict__ us, const float* __restrict__ W1,
       const float* __restrict__ b1, const float* __restrict__ W2,
       const float* __restrict__ b2, float* __restrict__ zs,
       float* __restrict__ hidG, unsigned* __restrict__ barG) {
    __shared__ float smem[NJS * BGB * 512 + 2048 + 2048 + 512 + 128 + 32];
    float* psum    = smem;                         // [8][8][512]  128 KB
    float* pa      = smem;                         // alias [32][256] (phase A)
    float* w2l     = smem;                         // alias [8][8][512] (W2 prefetch)
    float* z_loc   = smem + NJS * BGB * 512;       // [8][256]     8 KB
    float* hid_loc = z_loc + BGB * HH;             // [8][256]     8 KB
    float* b2s     = hid_loc + BGB * HH;           // [512]
    float* dvs     = b2s + 512;                    // [8][16]
    float* b1s     = dvs + 128;                    // [32]

    const int bg = blockIdx.x >> 3;
    const int hc = blockIdx.x & 7;                 // == XCD id: same-hc blocks
    const int t  = threadIdx.x;                    // share the W2 slice in L2
    const int b0 = bg * BGB;
    const int h0 = hc * HCH;
    const int n0 = h0 * CC;                        // = hc*512

    // ---- one-time preload ----
    const int ajc = t >> 5;                        // 0..31
    const int ah  = t & 31;
    float w1r[8];
    #pragma unroll
    for (int r = 0; r < 8; r++)
        w1r[r] = W1[(size_t)(ajc * 8 + r) * HH + h0 + ah];
    for (int i = t; i < 512; i += TPB) b2s[i] = b2[n0 + i];
    if (t < HCH) b1s[t] = b1[h0 + t];
    __syncthreads();

    unsigned* cnt = barG + (size_t)bg * 64;        // 256-B line per group

    const int sb  = t >> 7;                        // staging: 0..7
    const int sj2 = (t & 127) << 1;                // 0,2,..,254
    const int jsp = t >> 7;                        // phase-B: 0..7
    const int ct  = (t & 127) << 2;                // 0..508
    const int col = t & 511;                       // dz indices
    const int bh  = (t >> 9) << 2;                 // 0 or 4

    for (int k = 0; k < NSTEP; k++) {
        const size_t zk = (size_t)k * (BB * HH);

        // ---- stage z_loc (coherent 8B, coalesced) + dvs ----
        {
            float2 v = ld_coh2(&zs[zk + (size_t)(b0 + sb) * HH + sj2]);
            *(float2*)&z_loc[sb * HH + sj2] = v;
        }
        if (t < BGB * CC) {
            int b = t >> 4, c = t & 15;
            int kk = (k < 1) ? 1 : k;
            float v = 1.0f;                        // c==0: ts diff == 1
            if (c > 0)
                v = us[((size_t)kk * BB + b0 + b) * (CC - 1) + c - 1]
                  - us[((size_t)(kk - 1) * BB + b0 + b) * (CC - 1) + c - 1];
            dvs[b * CC + c] = v;
        }
        __syncthreads();

        // ---- phase A: partial hid[b][h0+ah] over 8 j's (W1 in regs) ----
        // UNCHANGED (bit-exact).
        {
            float acc[BGB];
            #pragma unroll
            for (int b = 0; b < BGB; b++) acc[b] = 0.f;
            #pragma unroll
            for (int r2 = 0; r2 < 2; r2++) {
                #pragma unroll
                for (int b = 0; b < BGB; b++) {
                    float4 zv = *(const float4*)&z_loc[b * HH + ajc * 8 + r2 * 4];
                    acc[b] += zv.x * w1r[r2 * 4 + 0] + zv.y * w1r[r2 * 4 + 1]
                            + zv.z * w1r[r2 * 4 + 2] + zv.w * w1r[r2 * 4 + 3];
                }
            }
            #pragma unroll
            for (int b = 0; b < BGB; b++)
                pa[ajc * 256 + b * HCH + ah] = acc[b];  // lane-stride 1: free
        }
        __syncthreads();
        if (t < BGB * HCH) {                       // reduce 32 partials, relu, publish
            float s = b1s[t & 31];
            #pragma unroll
            for (int q = 0; q < 32; q++) s += pa[q * 256 + t];  // stride 1
            st_coh(&hidG[(size_t)(b0 + (t >> 5)) * HH + h0 + (t & 31)],
                   fmaxf(s, 0.f));
        }
        __syncthreads();                           // pa reads done before w2l writes

        // ---- W2 prefetch into psum alias (values bit-identical; moves 128 KB
        //      of the L2 stream into the hid-barrier wait window) ----
        {
            const float* w2p = &W2[(size_t)(jsp * 32) * HC + n0 + ct];
            #pragma unroll
            for (int r = 0; r < 8; r++)
                *(f32x4*)&w2l[((jsp * 8 + r) << 9) + ct] =
                    *(const f32x4*)&w2p[(size_t)r * HC];
        }
        bg_barrier(cnt, 8u * (2u * (unsigned)k + 1u));   // hid complete

        // ---- stage hid_loc NATURAL layout (coherent 8B, coalesced) ----
        {
            float2 v = ld_coh2(&hidG[(size_t)(b0 + sb) * HH + sj2]);
            *(float2*)&hid_loc[sb * HH + sj2] = v;
        }
        __syncthreads();

        // ---- phase B: hid(8x256) @ W2-slice(256x512) ----
        // Chains UNCHANGED: ascending jq, quad order x,y,z,w; acc carries
        // across the jq<8 (LDS) and jq>=8 (global) halves. Same f32 inputs.
        {
            f32x4 acc[BGB];
            #pragma unroll
            for (int b = 0; b < BGB; b++) acc[b] = (f32x4){0.f, 0.f, 0.f, 0.f};
            const int jb = jsp * 32;
            const float* w2p = &W2[(size_t)jb * HC + n0 + ct];
            const float* w2c = &w2l[(jsp << 12) + ct];     // jsp*8*512
            #pragma unroll 2
            for (int jq = 0; jq < 8; jq += 4) {            // prefetched rows
                f32x4 w0 = *(const f32x4*)&w2c[(jq + 0) << 9];
                f32x4 w1 = *(const f32x4*)&w2c[(jq + 1) << 9];
                f32x4 w2v = *(const f32x4*)&w2c[(jq + 2) << 9];
                f32x4 w3 = *(const f32x4*)&w2c[(jq + 3) << 9];
                #pragma unroll
                for (int b = 0; b < BGB; b++) {
                    f32x4 h4 = *(const f32x4*)&hid_loc[b * HH + jb + jq]; // bcast
                    acc[b] = h4.x * w0  + acc[b];
                    acc[b] = h4.y * w1  + acc[b];
                    acc[b] = h4.z * w2v + acc[b];
                    acc[b] = h4.w * w3  + acc[b];
                }
            }
            #pragma unroll 2
            for (int jq = 8; jq < 32; jq += 4) {           // streamed rows
                f32x4 w0 = *(const f32x4*)&w2p[(size_t)(jq + 0) * HC];
                f32x4 w1 = *(const f32x4*)&w2p[(size_t)(jq + 1) * HC];
                f32x4 w2v = *(const f32x4*)&w2p[(size_t)(jq + 2) * HC];
                f32x4 w3 = *(const f32x4*)&w2p[(size_t)(jq + 3) * HC];
                #pragma unroll
                for (int b = 0; b < BGB; b++) {
                    f32x4 h4 = *(const f32x4*)&hid_loc[b * HH + jb + jq]; // bcast
                    acc[b] = h4.x * w0  + acc[b];
                    acc[b] = h4.y * w1  + acc[b];
                    acc[b] = h4.z * w2v + acc[b];
                    acc[b] = h4.w * w3  + acc[b];
                }
            }
            // store overwrites this wave's own w2l rows; all its (lockstep)
            // reads of those rows are complete. Other waves gated by barrier.
            #pragma unroll
            for (int b = 0; b < BGB; b++)
                *(f32x4*)&psum[((jsp * BGB + b) << 9) + ct] = acc[b];
        }
        __syncthreads();

        // ---- dz + z update: lane owns col; 16-lane shfl c-reduction ----
        // UNCHANGED (bit-exact).
        {
            #pragma unroll
            for (int q = 0; q < 4; q++) {
                int b = bh + q;
                float g = b2s[col];
                #pragma unroll
                for (int s = 0; s < NJS; s++)
                    g += psum[((s * BGB + b) << 9) + col];   // stride-1
                float v = fast_tanh(g) * dvs[b * CC + (col & 15)];
                v += __shfl_xor(v, 1);
                v += __shfl_xor(v, 2);
                v += __shfl_xor(v, 4);
                v += __shfl_xor(v, 8);
                if ((col & 15) == 0) {
                    int hl = col >> 4;
                    st_coh(&zs[zk + (size_t)(BB * HH) + (size_t)(b0 + b) * HH + h0 + hl],
                           z_loc[b * HH + h0 + hl] + v);     // dt == 1
                }
            }
        }
        bg_barrier(cnt, 8u * (2u * (unsigned)k + 2u));       // z[k+1] complete
    }
}

// ---------------------------------------------------------------------------
// out = tanh(z_seq @ dW1 + db1) @ dW2 + db2   — UNCHANGED from baseline.
// ---------------------------------------------------------------------------
__global__ void k_out(const float* __restrict__ zseq, const float* __restrict__ dW1,
                      const float* __restrict__ db1, const float* __restrict__ dW2,
                      const float* __restrict__ db2, float* __restrict__ out) {
    __shared__ float zt[16][HH];       // 16 KB
    __shared__ float act[16][2 * HH];  // 32 KB
    int r0 = blockIdx.x * 16;
    int t  = threadIdx.x;
    {
        const float4* src = (const float4*)(zseq + (size_t)r0 * HH);
        float4* dst = (float4*)&zt[0][0];
        for (int i = t; i < 1024; i += 256) dst[i] = src[i];
    }
    __syncthreads();
    {   // phase 1: act = tanh(z @ dW1 + db1), 512 cols
        int c0  = (t & 127) * 4;
        int rr0 = (t >> 7) * 8;
        float a[8][4];
        #pragma unroll
        for (int i = 0; i < 8; i++)
            #pragma unroll
            for (int q = 0; q < 4; q++) a[i][q] = 0.f;
        for (int j = 0; j < HH; j++) {
            float4 w = *(const float4*)&dW1[(size_t)j * 2 * HH + c0];
            #pragma unroll
            for (int i = 0; i < 8; i++) {
                float zv = zt[rr0 + i][j];
                a[i][0] += zv * w.x; a[i][1] += zv * w.y;
                a[i][2] += zv * w.z; a[i][3] += zv * w.w;
            }
        }
        float4 bias = *(const float4*)&db1[c0];
        #pragma unroll
        for (int i = 0; i < 8; i++) {
            act[rr0 + i][c0 + 0] = fast_tanh(a[i][0] + bias.x);
            act[rr0 + i][c0 + 1] = fast_tanh(a[i][1] + bias.y);
            act[rr0 + i][c0 + 2] = fast_tanh(a[i][2] + bias.z);
            act[rr0 + i][c0 + 3] = fast_tanh(a[i][3] + bias.w);
        }
    }
    __syncthreads();
    {   // phase 2: out = act @ dW2 + db2
        int rl = t >> 4;
        int y2 = t & 15;
        float o0 = 0.f, o1 = 0.f;
        #pragma unroll 4
        for (int j = 0; j < 2 * HH; j++) {
            float av = act[rl][j];
            float2 w = *(const float2*)&dW2[(size_t)j * YY + y2 * 2];
            o0 += av * w.x; o1 += av * w.y;
        }
        float2 bias = *(const float2*)&db2[y2 * 2];
        out[(size_t)(r0 + rl) * YY + y2 * 2]     = o0 + bias.x;
        out[(size_t)(r0 + rl) * YY + y2 * 2 + 1] = o1 + bias.y;
    }
}

// ---------------------------------------------------------------------------
extern "C" void kernel_launch(void* const* d_in, const int* in_sizes, int n_in,
                              void* d_out, int out_size, void* d_ws, size_t ws_size,
                              hipStream_t stream) {
    const float* us  = (const float*)d_in[1];
    const float* h0  = (const float*)d_in[2];
    const float* W1  = (const float*)d_in[3];
    const float* b1  = (const float*)d_in[4];
    const float* W2  = (const float*)d_in[5];
    const float* b2  = (const float*)d_in[6];
    const float* dW1 = (const float*)d_in[7];
    const float* db1 = (const float*)d_in[8];
    const float* dW2 = (const float*)d_in[9];
    const float* db2 = (const float*)d_in[10];
    float* out = (float*)d_out;

    float* zs   = (float*)d_ws;                          // L*B*H = 64 MB, [l*B+b][h]
    float* hidG = zs + (size_t)LL * BB * HH;             // B*H   = 256 KB
    unsigned* barG = (unsigned*)(hidG + (size_t)BB * HH); // 32 x 256 B = 8 KB

    hipMemcpyAsync(zs, h0, (size_t)BB * HH * sizeof(float),
                   hipMemcpyDeviceToDevice, stream);
    hipMemsetAsync(barG, 0, NBG * 64 * sizeof(unsigned), stream);

    k_scan<<<NBG * 8, TPB, 0, stream>>>(us, W1, b1, W2, b2, zs, hidG, barG);
    k_out<<<LL * BB / 16, 256, 0, stream>>>(zs, dW1, db1, dW2, db2, out);
}

// Round 11
// 3832.754 us; speedup vs baseline: 1.2244x; 1.2244x over previous
//
#include <hip/hip_runtime.h>
#include <math.h>

#define LL 256
#define BB 256
#define HH 256
#define CC 16
#define YY 32
#define HC (HH*CC)     // 4096
#define NSTEP (LL-1)   // 255
#define NBG 32         // batch groups
#define BGB 8          // batches per group
#define HCH 32         // h per chunk (=> 512 W2 cols per block)
#define TPB 1024
#define NJS 8          // phase-B j-split slices

typedef __attribute__((ext_vector_type(4))) float f32x4;

// fast tanh — IDENTICAL to the passing baseline (bit-exact frozen).
__device__ __forceinline__ float fast_tanh(float x) {
    float e = __expf(2.0f * x);
    return 1.0f - 2.0f / (e + 1.0f);
}

// coherence-point (device-coherent) access: bypasses the non-coherent
// per-XCD L2s. Used ONLY for the small cross-block z / hid exchange.
__device__ __forceinline__ float2 ld_coh2(const float* p) {
    union { unsigned long long u; float2 f; } cv;
    cv.u = __hip_atomic_load((const unsigned long long*)p,
                             __ATOMIC_RELAXED, __HIP_MEMORY_SCOPE_AGENT);
    return cv.f;
}
__device__ __forceinline__ void st_coh(float* p, float v) {
    __hip_atomic_store(p, v, __ATOMIC_RELAXED, __HIP_MEMORY_SCOPE_AGENT);
}

// 8-way sibling barrier, monotonic per-group counter (no reset).
// __syncthreads() drains vmem (vmcnt(0) before s_barrier) so all coherent
// stores are visible before the arrival add. 32 groups on 32 distinct lines.
__device__ __forceinline__ void bg_barrier(unsigned* cnt, unsigned target) {
    __syncthreads();
    if (threadIdx.x == 0) {
        __hip_atomic_fetch_add(cnt, 1u, __ATOMIC_RELAXED, __HIP_MEMORY_SCOPE_AGENT);
        while (__hip_atomic_load(cnt, __ATOMIC_RELAXED, __HIP_MEMORY_SCOPE_AGENT) < target)
            __builtin_amdgcn_s_sleep(1);
    }
    __syncthreads();
}

// ---------------------------------------------------------------------------
// persistent scan: 256 blocks = 32 bg x 8 hc, 1024 threads, 1 block/CU
// (LDS 147 KB). __launch_bounds__(TPB,4): 128-VGPR cap.
// r6 STRUCTURE FROZEN (passing, 3513 us, absmax 0.03417969). Single delta:
// each thread caches its first 8 W2 rows (jq 0..7: 32 VGPRs) ONCE before the
// k-loop; phase B reads those rows from registers, streaming only jq 8..31
// from L2 (-25% L2 traffic, zero per-step overhead, zero scheduling change —
// r10 proved substituting cached-identical W2 values is numerically exact,
// and that PER-STEP prefetch/syncs are what de-synchronize the XCD and
// break L2 residency; this one-time cache avoids both).
// ---------------------------------------------------------------------------
__global__ void __launch_bounds__(TPB, 4)
k_scan(const float* __restrict__ us, const float* __restrict__ W1,
       const float* __restrict__ b1, const float* __restrict__ W2,
       const float* __restrict__ b2, float* __restrict__ zs,
       float* __restrict__ hidG, unsigned* __restrict__ barG) {
    __shared__ float smem[NJS * BGB * 512 + 2048 + 2048 + 512 + 128 + 32];
    float* psum    = smem;                         // [8][8][512]  128 KB
    float* pa      = smem;                         // alias [32][256] (phase A)
    float* z_loc   = smem + NJS * BGB * 512;       // [8][256]     8 KB
    float* hid_loc = z_loc + BGB * HH;             // [8][256]     8 KB
    float* b2s     = hid_loc + BGB * HH;           // [512]
    float* dvs     = b2s + 512;                    // [8][16]
    float* b1s     = dvs + 128;                    // [32]

    const int bg = blockIdx.x >> 3;
    const int hc = blockIdx.x & 7;                 // == XCD id: same-hc blocks
    const int t  = threadIdx.x;                    // share the W2 slice in L2
    const int b0 = bg * BGB;
    const int h0 = hc * HCH;
    const int n0 = h0 * CC;                        // = hc*512

    // ---- one-time preload ----
    const int ajc = t >> 5;                        // 0..31
    const int ah  = t & 31;
    float w1r[8];
    #pragma unroll
    for (int r = 0; r < 8; r++)
        w1r[r] = W1[(size_t)(ajc * 8 + r) * HH + h0 + ah];
    for (int i = t; i < 512; i += TPB) b2s[i] = b2[n0 + i];
    if (t < HCH) b1s[t] = b1[h0 + t];

    const int jsp = t >> 7;                        // phase-B: 0..7
    const int ct  = (t & 127) << 2;                // 0..508
    // persistent W2 register cache: this thread's rows jq 0..7 (32 VGPRs).
    // Same addresses phase B's jq<8 loads used -> identical f32 bits.
    f32x4 w2r[8];
    {
        const float* w2p = &W2[(size_t)(jsp * 32) * HC + n0 + ct];
        #pragma unroll
        for (int r = 0; r < 8; r++)
            w2r[r] = *(const f32x4*)&w2p[(size_t)r * HC];
    }
    __syncthreads();

    unsigned* cnt = barG + (size_t)bg * 64;        // 256-B line per group

    const int sb  = t >> 7;                        // staging: 0..7
    const int sj2 = (t & 127) << 1;                // 0,2,..,254
    const int col = t & 511;                       // dz indices
    const int bh  = (t >> 9) << 2;                 // 0 or 4

    for (int k = 0; k < NSTEP; k++) {
        const size_t zk = (size_t)k * (BB * HH);

        // ---- stage z_loc (coherent 8B, coalesced) + dvs ----
        {
            float2 v = ld_coh2(&zs[zk + (size_t)(b0 + sb) * HH + sj2]);
            *(float2*)&z_loc[sb * HH + sj2] = v;
        }
        if (t < BGB * CC) {
            int b = t >> 4, c = t & 15;
            int kk = (k < 1) ? 1 : k;
            float v = 1.0f;                        // c==0: ts diff == 1
            if (c > 0)
                v = us[((size_t)kk * BB + b0 + b) * (CC - 1) + c - 1]
                  - us[((size_t)(kk - 1) * BB + b0 + b) * (CC - 1) + c - 1];
            dvs[b * CC + c] = v;
        }
        __syncthreads();

        // ---- phase A: partial hid[b][h0+ah] over 8 j's (W1 in regs) ----
        // UNCHANGED (bit-exact).
        {
            float acc[BGB];
            #pragma unroll
            for (int b = 0; b < BGB; b++) acc[b] = 0.f;
            #pragma unroll
            for (int r2 = 0; r2 < 2; r2++) {
                #pragma unroll
                for (int b = 0; b < BGB; b++) {
                    float4 zv = *(const float4*)&z_loc[b * HH + ajc * 8 + r2 * 4];
                    acc[b] += zv.x * w1r[r2 * 4 + 0] + zv.y * w1r[r2 * 4 + 1]
                            + zv.z * w1r[r2 * 4 + 2] + zv.w * w1r[r2 * 4 + 3];
                }
            }
            #pragma unroll
            for (int b = 0; b < BGB; b++)
                pa[ajc * 256 + b * HCH + ah] = acc[b];  // lane-stride 1: free
        }
        __syncthreads();
        if (t < BGB * HCH) {                       // reduce 32 partials, relu, publish
            float s = b1s[t & 31];
            #pragma unroll
            for (int q = 0; q < 32; q++) s += pa[q * 256 + t];  // stride 1
            st_coh(&hidG[(size_t)(b0 + (t >> 5)) * HH + h0 + (t & 31)],
                   fmaxf(s, 0.f));
        }
        bg_barrier(cnt, 8u * (2u * (unsigned)k + 1u));   // hid complete

        // ---- stage hid_loc NATURAL layout (coherent 8B, coalesced) ----
        {
            float2 v = ld_coh2(&hidG[(size_t)(b0 + sb) * HH + sj2]);
            *(float2*)&hid_loc[sb * HH + sj2] = v;
        }
        __syncthreads();

        // ---- phase B: hid(8x256) @ W2-slice(256x512) ----
        // Chains UNCHANGED: ascending jq, quad order x,y,z,w; acc carries
        // across the jq<8 (register) and jq>=8 (streamed) halves. Identical
        // f32 inputs in identical order -> bit-exact.
        {
            f32x4 acc[BGB];
            #pragma unroll
            for (int b = 0; b < BGB; b++) acc[b] = (f32x4){0.f, 0.f, 0.f, 0.f};
            const int jb = jsp * 32;
            const float* w2p = &W2[(size_t)jb * HC + n0 + ct];
            #pragma unroll
            for (int jq = 0; jq < 8; jq += 4) {            // register-cached rows
                f32x4 w0 = w2r[jq + 0];
                f32x4 w1 = w2r[jq + 1];
                f32x4 w2v = w2r[jq + 2];
                f32x4 w3 = w2r[jq + 3];
                #pragma unroll
                for (int b = 0; b < BGB; b++) {
                    f32x4 h4 = *(const f32x4*)&hid_loc[b * HH + jb + jq]; // bcast
                    acc[b] = h4.x * w0  + acc[b];
                    acc[b] = h4.y * w1  + acc[b];
                    acc[b] = h4.z * w2v + acc[b];
                    acc[b] = h4.w * w3  + acc[b];
                }
            }
            #pragma unroll 2
            for (int jq = 8; jq < 32; jq += 4) {           // streamed rows
                f32x4 w0 = *(const f32x4*)&w2p[(size_t)(jq + 0) * HC];
                f32x4 w1 = *(const f32x4*)&w2p[(size_t)(jq + 1) * HC];
                f32x4 w2v = *(const f32x4*)&w2p[(size_t)(jq + 2) * HC];
                f32x4 w3 = *(const f32x4*)&w2p[(size_t)(jq + 3) * HC];
                #pragma unroll
                for (int b = 0; b < BGB; b++) {
                    f32x4 h4 = *(const f32x4*)&hid_loc[b * HH + jb + jq]; // bcast
                    acc[b] = h4.x * w0  + acc[b];
                    acc[b] = h4.y * w1  + acc[b];
                    acc[b] = h4.z * w2v + acc[b];
                    acc[b] = h4.w * w3  + acc[b];
                }
            }
            #pragma unroll
            for (int b = 0; b < BGB; b++)
                *(f32x4*)&psum[((jsp * BGB + b) << 9) + ct] = acc[b];
        }
        __syncthreads();

        // ---- dz + z update: lane owns col; 16-lane shfl c-reduction ----
        // UNCHANGED (bit-exact).
        {
            #pragma unroll
            for (int q = 0; q < 4; q++) {
                int b = bh + q;
                float g = b2s[col];
                #pragma unroll
                for (int s = 0; s < NJS; s++)
                    g += psum[((s * BGB + b) << 9) + col];   // stride-1
                float v = fast_tanh(g) * dvs[b * CC + (col & 15)];
                v += __shfl_xor(v, 1);
                v += __shfl_xor(v, 2);
                v += __shfl_xor(v, 4);
                v += __shfl_xor(v, 8);
                if ((col & 15) == 0) {
                    int hl = col >> 4;
                    st_coh(&zs[zk + (size_t)(BB * HH) + (size_t)(b0 + b) * HH + h0 + hl],
                           z_loc[b * HH + h0 + hl] + v);     // dt == 1
                }
            }
        }
        bg_barrier(cnt, 8u * (2u * (unsigned)k + 2u));       // z[k+1] complete
    }
}

// ---------------------------------------------------------------------------
// out = tanh(z_seq @ dW1 + db1) @ dW2 + db2   — UNCHANGED from baseline.
// ---------------------------------------------------------------------------
__global__ void k_out(const float* __restrict__ zseq, const float* __restrict__ dW1,
                      const float* __restrict__ db1, const float* __restrict__ dW2,
                      const float* __restrict__ db2, float* __restrict__ out) {
    __shared__ float zt[16][HH];       // 16 KB
    __shared__ float act[16][2 * HH];  // 32 KB
    int r0 = blockIdx.x * 16;
    int t  = threadIdx.x;
    {
        const float4* src = (const float4*)(zseq + (size_t)r0 * HH);
        float4* dst = (float4*)&zt[0][0];
        for (int i = t; i < 1024; i += 256) dst[i] = src[i];
    }
    __syncthreads();
    {   // phase 1: act = tanh(z @ dW1 + db1), 512 cols
        int c0  = (t & 127) * 4;
        int rr0 = (t >> 7) * 8;
        float a[8][4];
        #pragma unroll
        for (int i = 0; i < 8; i++)
            #pragma unroll
            for (int q = 0; q < 4; q++) a[i][q] = 0.f;
        for (int j = 0; j < HH; j++) {
            float4 w = *(const float4*)&dW1[(size_t)j * 2 * HH + c0];
            #pragma unroll
            for (int i = 0; i < 8; i++) {
                float zv = zt[rr0 + i][j];
                a[i][0] += zv * w.x; a[i][1] += zv * w.y;
                a[i][2] += zv * w.z; a[i][3] += zv * w.w;
            }
        }
        float4 bias = *(const float4*)&db1[c0];
        #pragma unroll
        for (int i = 0; i < 8; i++) {
            act[rr0 + i][c0 + 0] = fast_tanh(a[i][0] + bias.x);
            act[rr0 + i][c0 + 1] = fast_tanh(a[i][1] + bias.y);
            act[rr0 + i][c0 + 2] = fast_tanh(a[i][2] + bias.z);
            act[rr0 + i][c0 + 3] = fast_tanh(a[i][3] + bias.w);
        }
    }
    __syncthreads();
    {   // phase 2: out = act @ dW2 + db2
        int rl = t >> 4;
        int y2 = t & 15;
        float o0 = 0.f, o1 = 0.f;
        #pragma unroll 4
        for (int j = 0; j < 2 * HH; j++) {
            float av = act[rl][j];
            float2 w = *(const float2*)&dW2[(size_t)j * YY + y2 * 2];
            o0 += av * w.x; o1 += av * w.y;
        }
        float2 bias = *(const float2*)&db2[y2 * 2];
        out[(size_t)(r0 + rl) * YY + y2 * 2]     = o0 + bias.x;
        out[(size_t)(r0 + rl) * YY + y2 * 2 + 1] = o1 + bias.y;
    }
}

// ---------------------------------------------------------------------------
extern "C" void kernel_launch(void* const* d_in, const int* in_sizes, int n_in,
                              void* d_out, int out_size, void* d_ws, size_t ws_size,
                              hipStream_t stream) {
    const float* us  = (const float*)d_in[1];
    const float* h0  = (const float*)d_in[2];
    const float* W1  = (const float*)d_in[3];
    const float* b1  = (const float*)d_in[4];
    const float* W2  = (const float*)d_in[5];
    const float* b2  = (const float*)d_in[6];
    const float* dW1 = (const float*)d_in[7];
    const float* db1 = (const float*)d_in[8];
    const float* dW2 = (const float*)d_in[9];
    const float* db2 = (const float*)d_in[10];
    float* out = (float*)d_out;

    float* zs   = (float*)d_ws;                          // L*B*H = 64 MB, [l*B+b][h]
    float* hidG = zs + (size_t)LL * BB * HH;             // B*H   = 256 KB
    unsigned* barG = (unsigned*)(hidG + (size_t)BB * HH); // 32 x 256 B = 8 KB

    hipMemcpyAsync(zs, h0, (size_t)BB * HH * sizeof(float),
                   hipMemcpyDeviceToDevice, stream);
    hipMemsetAsync(barG, 0, NBG * 64 * sizeof(unsigned), stream);

    k_scan<<<NBG * 8, TPB, 0, stream>>>(us, W1, b1, W2, b2, zs, hidG, barG);
    k_out<<<LL * BB / 16, 256, 0, stream>>>(zs, dW1, db1, dW2, db2, out);
}

// Round 12
// 3488.048 us; speedup vs baseline: 1.3455x; 1.0988x over previous
//
#include <hip/hip_runtime.h>
#include <math.h>

#define LL 256
#define BB 256
#define HH 256
#define CC 16
#define YY 32
#define HC (HH*CC)     // 4096
#define NSTEP (LL-1)   // 255
#define NBG 32         // batch groups
#define BGB 8          // batches per group
#define HCH 32         // h per chunk (=> 512 W2 cols per block)
#define TPB 1024
#define NJS 8          // phase-B j-split slices

typedef __attribute__((ext_vector_type(4))) float f32x4;

// fast tanh — IDENTICAL to the passing baseline (bit-exact frozen).
__device__ __forceinline__ float fast_tanh(float x) {
    float e = __expf(2.0f * x);
    return 1.0f - 2.0f / (e + 1.0f);
}

// coherence-point (device-coherent) access: bypasses the non-coherent
// per-XCD L2s. Used ONLY for the small cross-block z / hid exchange.
__device__ __forceinline__ float2 ld_coh2(const float* p) {
    union { unsigned long long u; float2 f; } cv;
    cv.u = __hip_atomic_load((const unsigned long long*)p,
                             __ATOMIC_RELAXED, __HIP_MEMORY_SCOPE_AGENT);
    return cv.f;
}
__device__ __forceinline__ void st_coh(float* p, float v) {
    __hip_atomic_store(p, v, __ATOMIC_RELAXED, __HIP_MEMORY_SCOPE_AGENT);
}

// 8-way sibling barrier, monotonic per-group counter (no reset).
// __syncthreads() drains vmem (vmcnt(0) before s_barrier) so all coherent
// stores are visible before the arrival add. 32 groups on 32 distinct lines.
__device__ __forceinline__ void bg_barrier(unsigned* cnt, unsigned target) {
    __syncthreads();
    if (threadIdx.x == 0) {
        __hip_atomic_fetch_add(cnt, 1u, __ATOMIC_RELAXED, __HIP_MEMORY_SCOPE_AGENT);
        while (__hip_atomic_load(cnt, __ATOMIC_RELAXED, __HIP_MEMORY_SCOPE_AGENT) < target)
            __builtin_amdgcn_s_sleep(1);
    }
    __syncthreads();
}

// ---------------------------------------------------------------------------
// persistent scan: 256 blocks = 32 bg x 8 hc, 1024 threads, 1 block/CU
// (LDS 147 KB). __launch_bounds__(TPB,4): 128-VGPR cap, no spill.
// BEST VERIFIED CONFIGURATION (r6: 3513 us, absmax 0.03417969).
// Structural ceiling documented by the session ledger:
//  - arithmetic frozen: MFMA / pk-fma / any chain reorder re-rolls a chaos
//    lottery across 255 amplifying steps that straddles the 0.052 threshold
//    (r1-r4, r8, r9 all failed on this).
//  - scheduling frozen: per-step prefetch (r10), W2 reg-cache (r11), in-block
//    dual pipeline (r7), 2-blocks/CU repartition (r9) all regressed or broke —
//    the 8-sibling x 32-group XCD synchronization is latency-critical and
//    any perturbation costs more than it hides.
// Step budget: ~6.9 us VALU issue + ~6.9 us cross-block exchange/barrier.
// ---------------------------------------------------------------------------
__global__ void __launch_bounds__(TPB, 4)
k_scan(const float* __restrict__ us, const float* __restrict__ W1,
       const float* __restrict__ b1, const float* __restrict__ W2,
       const float* __restrict__ b2, float* __restrict__ zs,
       float* __restrict__ hidG, unsigned* __restrict__ barG) {
    __shared__ float smem[NJS * BGB * 512 + 2048 + 2048 + 512 + 128 + 32];
    float* psum    = smem;                         // [8][8][512]  128 KB
    float* pa      = smem;                         // alias [32][256] (phase A)
    float* z_loc   = smem + NJS * BGB * 512;       // [8][256]     8 KB
    float* hid_loc = z_loc + BGB * HH;             // [8][256]     8 KB
    float* b2s     = hid_loc + BGB * HH;           // [512]
    float* dvs     = b2s + 512;                    // [8][16]
    float* b1s     = dvs + 128;                    // [32]

    const int bg = blockIdx.x >> 3;
    const int hc = blockIdx.x & 7;                 // == XCD id: same-hc blocks
    const int t  = threadIdx.x;                    // share the W2 slice in L2
    const int b0 = bg * BGB;
    const int h0 = hc * HCH;
    const int n0 = h0 * CC;                        // = hc*512

    // ---- one-time preload ----
    const int ajc = t >> 5;                        // 0..31
    const int ah  = t & 31;
    float w1r[8];
    #pragma unroll
    for (int r = 0; r < 8; r++)
        w1r[r] = W1[(size_t)(ajc * 8 + r) * HH + h0 + ah];
    for (int i = t; i < 512; i += TPB) b2s[i] = b2[n0 + i];
    if (t < HCH) b1s[t] = b1[h0 + t];
    __syncthreads();

    unsigned* cnt = barG + (size_t)bg * 64;        // 256-B line per group

    const int sb  = t >> 7;                        // staging: 0..7
    const int sj2 = (t & 127) << 1;                // 0,2,..,254
    const int jsp = t >> 7;                        // phase-B: 0..7
    const int ct  = (t & 127) << 2;                // 0..508
    const int col = t & 511;                       // dz indices
    const int bh  = (t >> 9) << 2;                 // 0 or 4

    for (int k = 0; k < NSTEP; k++) {
        const size_t zk = (size_t)k * (BB * HH);

        // ---- stage z_loc (coherent 8B, coalesced) + dvs ----
        {
            float2 v = ld_coh2(&zs[zk + (size_t)(b0 + sb) * HH + sj2]);
            *(float2*)&z_loc[sb * HH + sj2] = v;
        }
        if (t < BGB * CC) {
            int b = t >> 4, c = t & 15;
            int kk = (k < 1) ? 1 : k;
            float v = 1.0f;                        // c==0: ts diff == 1
            if (c > 0)
                v = us[((size_t)kk * BB + b0 + b) * (CC - 1) + c - 1]
                  - us[((size_t)(kk - 1) * BB + b0 + b) * (CC - 1) + c - 1];
            dvs[b * CC + c] = v;
        }
        __syncthreads();

        // ---- phase A: partial hid[b][h0+ah] over 8 j's (W1 in regs) ----
        {
            float acc[BGB];
            #pragma unroll
            for (int b = 0; b < BGB; b++) acc[b] = 0.f;
            #pragma unroll
            for (int r2 = 0; r2 < 2; r2++) {
                #pragma unroll
                for (int b = 0; b < BGB; b++) {
                    float4 zv = *(const float4*)&z_loc[b * HH + ajc * 8 + r2 * 4];
                    acc[b] += zv.x * w1r[r2 * 4 + 0] + zv.y * w1r[r2 * 4 + 1]
                            + zv.z * w1r[r2 * 4 + 2] + zv.w * w1r[r2 * 4 + 3];
                }
            }
            #pragma unroll
            for (int b = 0; b < BGB; b++)
                pa[ajc * 256 + b * HCH + ah] = acc[b];  // lane-stride 1: free
        }
        __syncthreads();
        if (t < BGB * HCH) {                       // reduce 32 partials, relu, publish
            float s = b1s[t & 31];
            #pragma unroll
            for (int q = 0; q < 32; q++) s += pa[q * 256 + t];  // stride 1
            st_coh(&hidG[(size_t)(b0 + (t >> 5)) * HH + h0 + (t & 31)],
                   fmaxf(s, 0.f));
        }
        bg_barrier(cnt, 8u * (2u * (unsigned)k + 1u));   // hid complete

        // ---- stage hid_loc NATURAL layout (coherent 8B, coalesced) ----
        {
            float2 v = ld_coh2(&hidG[(size_t)(b0 + sb) * HH + sj2]);
            *(float2*)&hid_loc[sb * HH + sj2] = v;
        }
        __syncthreads();

        // ---- phase B: hid(8x256) @ W2-slice(256x512) ----
        {
            f32x4 acc[BGB];
            #pragma unroll
            for (int b = 0; b < BGB; b++) acc[b] = (f32x4){0.f, 0.f, 0.f, 0.f};
            const int jb = jsp * 32;
            const float* w2p = &W2[(size_t)jb * HC + n0 + ct];
            #pragma unroll 2
            for (int jq = 0; jq < 32; jq += 4) {
                f32x4 w0 = *(const f32x4*)&w2p[(size_t)(jq + 0) * HC];
                f32x4 w1 = *(const f32x4*)&w2p[(size_t)(jq + 1) * HC];
                f32x4 w2v = *(const f32x4*)&w2p[(size_t)(jq + 2) * HC];
                f32x4 w3 = *(const f32x4*)&w2p[(size_t)(jq + 3) * HC];
                #pragma unroll
                for (int b = 0; b < BGB; b++) {
                    f32x4 h4 = *(const f32x4*)&hid_loc[b * HH + jb + jq]; // bcast
                    acc[b] = h4.x * w0  + acc[b];
                    acc[b] = h4.y * w1  + acc[b];
                    acc[b] = h4.z * w2v + acc[b];
                    acc[b] = h4.w * w3  + acc[b];
                }
            }
            #pragma unroll
            for (int b = 0; b < BGB; b++)
                *(f32x4*)&psum[((jsp * BGB + b) << 9) + ct] = acc[b];
        }
        __syncthreads();

        // ---- dz + z update: lane owns col; 16-lane shfl c-reduction ----
        {
            #pragma unroll
            for (int q = 0; q < 4; q++) {
                int b = bh + q;
                float g = b2s[col];
                #pragma unroll
                for (int s = 0; s < NJS; s++)
                    g += psum[((s * BGB + b) << 9) + col];   // stride-1
                float v = fast_tanh(g) * dvs[b * CC + (col & 15)];
                v += __shfl_xor(v, 1);
                v += __shfl_xor(v, 2);
                v += __shfl_xor(v, 4);
                v += __shfl_xor(v, 8);
                if ((col & 15) == 0) {
                    int hl = col >> 4;
                    st_coh(&zs[zk + (size_t)(BB * HH) + (size_t)(b0 + b) * HH + h0 + hl],
                           z_loc[b * HH + h0 + hl] + v);     // dt == 1
                }
            }
        }
        bg_barrier(cnt, 8u * (2u * (unsigned)k + 2u));       // z[k+1] complete
    }
}

// ---------------------------------------------------------------------------
// out = tanh(z_seq @ dW1 + db1) @ dW2 + db2   — UNCHANGED from baseline.
// ---------------------------------------------------------------------------
__global__ void k_out(const float* __restrict__ zseq, const float* __restrict__ dW1,
                      const float* __restrict__ db1, const float* __restrict__ dW2,
                      const float* __restrict__ db2, float* __restrict__ out) {
    __shared__ float zt[16][HH];       // 16 KB
    __shared__ float act[16][2 * HH];  // 32 KB
    int r0 = blockIdx.x * 16;
    int t  = threadIdx.x;
    {
        const float4* src = (const float4*)(zseq + (size_t)r0 * HH);
        float4* dst = (float4*)&zt[0][0];
        for (int i = t; i < 1024; i += 256) dst[i] = src[i];
    }
    __syncthreads();
    {   // phase 1: act = tanh(z @ dW1 + db1), 512 cols
        int c0  = (t & 127) * 4;
        int rr0 = (t >> 7) * 8;
        float a[8][4];
        #pragma unroll
        for (int i = 0; i < 8; i++)
            #pragma unroll
            for (int q = 0; q < 4; q++) a[i][q] = 0.f;
        for (int j = 0; j < HH; j++) {
            float4 w = *(const float4*)&dW1[(size_t)j * 2 * HH + c0];
            #pragma unroll
            for (int i = 0; i < 8; i++) {
                float zv = zt[rr0 + i][j];
                a[i][0] += zv * w.x; a[i][1] += zv * w.y;
                a[i][2] += zv * w.z; a[i][3] += zv * w.w;
            }
        }
        float4 bias = *(const float4*)&db1[c0];
        #pragma unroll
        for (int i = 0; i < 8; i++) {
            act[rr0 + i][c0 + 0] = fast_tanh(a[i][0] + bias.x);
            act[rr0 + i][c0 + 1] = fast_tanh(a[i][1] + bias.y);
            act[rr0 + i][c0 + 2] = fast_tanh(a[i][2] + bias.z);
            act[rr0 + i][c0 + 3] = fast_tanh(a[i][3] + bias.w);
        }
    }
    __syncthreads();
    {   // phase 2: out = act @ dW2 + db2
        int rl = t >> 4;
        int y2 = t & 15;
        float o0 = 0.f, o1 = 0.f;
        #pragma unroll 4
        for (int j = 0; j < 2 * HH; j++) {
            float av = act[rl][j];
            float2 w = *(const float2*)&dW2[(size_t)j * YY + y2 * 2];
            o0 += av * w.x; o1 += av * w.y;
        }
        float2 bias = *(const float2*)&db2[y2 * 2];
        out[(size_t)(r0 + rl) * YY + y2 * 2]     = o0 + bias.x;
        out[(size_t)(r0 + rl) * YY + y2 * 2 + 1] = o1 + bias.y;
    }
}

// ---------------------------------------------------------------------------
extern "C" void kernel_launch(void* const* d_in, const int* in_sizes, int n_in,
                              void* d_out, int out_size, void* d_ws, size_t ws_size,
                              hipStream_t stream) {
    const float* us  = (const float*)d_in[1];
    const float* h0  = (const float*)d_in[2];
    const float* W1  = (const float*)d_in[3];
    const float* b1  = (const float*)d_in[4];
    const float* W2  = (const float*)d_in[5];
    const float* b2  = (const float*)d_in[6];
    const float* dW1 = (const float*)d_in[7];
    const float* db1 = (const float*)d_in[8];
    const float* dW2 = (const float*)d_in[9];
    const float* db2 = (const float*)d_in[10];
    float* out = (float*)d_out;

    float* zs   = (float*)d_ws;                          // L*B*H = 64 MB, [l*B+b][h]
    float* hidG = zs + (size_t)LL * BB * HH;             // B*H   = 256 KB
    unsigned* barG = (unsigned*)(hidG + (size_t)BB * HH); // 32 x 256 B = 8 KB

    hipMemcpyAsync(zs, h0, (size_t)BB * HH * sizeof(float),
                   hipMemcpyDeviceToDevice, stream);
    hipMemsetAsync(barG, 0, NBG * 64 * sizeof(unsigned), stream);

    k_scan<<<NBG * 8, TPB, 0, stream>>>(us, W1, b1, W2, b2, zs, hidG, barG);
    k_out<<<LL * BB / 16, 256, 0, stream>>>(zs, dW1, db1, dW2, db2, out);
}